// Round 7
// baseline (12941.821 us; speedup 1.0000x reference)
//
#include <hip/hip_runtime.h>
#include <math.h>

#define NT     365
#define NGRID  3000
#define NX     20
#define H      256
#define CPB    15
#define NBLK   (NGRID/CPB)     // 200 blocks, 1 per CU
#define THREADS 512            // 8 waves, 2 per SIMD -> 256 unified regs/wave

// packed weight sizes (ushorts)
// wpk HI-ONLY, pi-ordered: [g 16][pi 16][q 4][lane 64][e 8]
//   pi 0..7  = h-kaps  (k 256..511, w_hh) -> consumed in G1
//   pi 8..15 = x-kaps  (k 0..255,  w_ih) -> consumed in G2
#define WPK_US   (16*16*4*64*8)   // 524,288
#define WPKIN_US (16*2*64*8)      // 16,384

typedef short v8s __attribute__((ext_vector_type(8)));
typedef float v4f __attribute__((ext_vector_type(4)));
#define MFMA_BF16 __builtin_amdgcn_mfma_f32_16x16x32_bf16

__device__ __forceinline__ unsigned short f2bf(float f) {
    unsigned int u = __float_as_uint(f);
    u += 0x7fffu + ((u >> 16) & 1u);          // RTNE
    return (unsigned short)(u >> 16);
}
__device__ __forceinline__ float bf2f(unsigned short h) {
    return __uint_as_float(((unsigned int)h) << 16);
}
__device__ __forceinline__ float sigm(float x)  { return 1.0f / (1.0f + __expf(-x)); }
__device__ __forceinline__ float tanh_f(float x){ return 2.0f * sigm(2.0f * x) - 1.0f; }

// ---------------- weight pre-pack (identical to R6) ----------------
__global__ void prep_kernel(const float* __restrict__ w_in,
                            const float* __restrict__ w_ih,
                            const float* __restrict__ w_hh,
                            const float* __restrict__ b_ih,
                            const float* __restrict__ b_hh,
                            unsigned short* __restrict__ wpk,
                            unsigned short* __restrict__ wpkin,
                            float* __restrict__ bsum) {
    int idx = blockIdx.x * 256 + threadIdx.x;
    if (idx < WPK_US) {
        int e    = idx & 7;
        int lane = (idx >> 3) & 63;
        int q    = (idx >> 9) & 3;
        int gk   = idx >> 11;            // 0..255
        int pi   = gk & 15, g = gk >> 4;
        int kap  = (pi < 8) ? pi + 8 : pi - 8;   // pi 0..7 = h, 8..15 = x
        int k = kap * 32 + ((lane >> 4) << 3) + e;
        int j = q * 256 + g * 16 + (lane & 15);
        float wv = (k < 256) ? w_ih[j * 256 + k] : w_hh[j * 256 + (k - 256)];
        wpk[idx] = f2bf(wv);             // hi only
    }
    if (idx < WPKIN_US) {
        int e    = idx & 7;
        int lane = (idx >> 3) & 63;
        int d    = (idx >> 9) & 1;
        int tau  = idx >> 10;            // 0..15
        int k = ((lane >> 4) << 3) + e;
        int n = tau * 16 + (lane & 15);
        float wv = (k < NX + 1) ? w_in[n * (NX + 1) + k] : 0.0f;
        unsigned short hi = f2bf(wv);
        wpkin[idx] = d ? f2bf(wv - bf2f(hi)) : hi;
    }
    if (idx < 4 * H) bsum[idx] = b_ih[idx] + b_hh[idx];
}

// ---------------- main persistent LSTM ----------------
// R15: break the 6-round VGPR=64 logjam by changing BLOCK SHAPE.
//  Evidence: 1024-thr blocks force 4 waves/SIMD -> 128 unified regs/wave,
//  compiler splits 64 arch + 64 acc -> every reg-resident weight scheme
//  spilled (R9/R10/R12/R13); gload_lds defeats the L2 residency this
//  kernel's 365x re-read stream depends on (R14: FETCH 61MB -> 12GB).
//  Design:
//  - 512 threads, 8 waves (2/SIMD -> 256 regs/wave). Wave w owns output
//    groups gA=w, gB=w+8; A-fragment shared per pi -> same total MFMAs.
//  - 2-pi-deep register double-buffer (4 bufs x 32 regs) of PLAIN vector
//    loads (L2-cached); compiler auto-vmcnt on reg deps; loads fly across
//    raw lgkm-only barriers (correctness proven R4-R6).
//  - LDS persists pi14 q0-2 + pi15 full per (wave,group) = 112 KB (R2-style);
//    pi14-q3 streamed as 2 chunks. Stream 912 KB/step via L2.
//  - 3-barrier schedule unchanged.
__global__ __attribute__((amdgpu_flat_work_group_size(THREADS, THREADS),
                          amdgpu_waves_per_eu(2, 2)))
void lstm_main(const float* __restrict__ x,
               const float* __restrict__ y,
               const float* __restrict__ b_in,
               const float* __restrict__ w_out,
               const float* __restrict__ b_out,
               const unsigned short* __restrict__ wpk,
               const unsigned short* __restrict__ wpkin,
               const float* __restrict__ bsum,
               float* __restrict__ out) {
    // fragment-major activation buffers: [pi][lane*8+e], lane = qp*16 + m
    __shared__ __align__(16) unsigned short Agh[16][512];   // 16 KB
    __shared__ __align__(16) unsigned short Agl[16][512];   // 16 KB
    __shared__ __align__(16) unsigned short Xh[512];        // 1 KB
    __shared__ __align__(16) unsigned short Xl[512];        // 1 KB
    __shared__ __align__(16) unsigned short BwB[16][2048];  // 64 KB pi-15 [w*2+grp]
    __shared__ __align__(16) unsigned short BwA[16][1536];  // 48 KB pi-14 q0-2
    __shared__ float y_part[16][16];
    // total ~147 KB -> 1 block/CU

    const int tid  = threadIdx.x;
    const int w    = tid >> 6;          // wave 0..7; owns groups w and w+8
    const int lane = tid & 63;
    const int col  = lane & 15;
    const int quad = lane >> 4;
    const int g0   = blockIdx.x * CPB;

    // per-wave constants: lane owns hidden indices jhA = w*16+col, jhB = +128
    const int   jhA  = w * 16 + col;
    const int   jhB  = jhA + 128;
    const float b_iA = bsum[jhA],       b_iB = bsum[jhB];
    const float b_fA = bsum[256 + jhA], b_fB = bsum[256 + jhB];
    const float b_gA = bsum[512 + jhA], b_gB = bsum[512 + jhB];
    const float b_oA = bsum[768 + jhA], b_oB = bsum[768 + jhB];
    const float woA  = w_out[jhA],      woB  = w_out[jhB];
    const float bi_xA = b_in[jhA],      bi_xB = b_in[jhB];
    const float bout = b_out[0];
    const int   hsA  = w >> 1;                    // jhA>>5, 0..3
    const int   pi_hA = hsA,     pi_hB = hsA + 4; // h write planes
    const int   pi_xA = 8 + hsA, pi_xB = 12 + hsA;// x0 write planes
    const int   qp_w = (jhA >> 3) & 3;            // same for both groups
    const int   e_w  = jhA & 7;
    // per-lane global byte bases of this wave's two weight slices (64 KB each)
    const char* gbaseA = (const char*)wpk + ((size_t)w << 16) + (lane << 4);
    const char* gbaseB = (const char*)wpk + ((size_t)(w + 8) << 16) + (lane << 4);
    const unsigned short* bxA = wpkin + w * 1024 + lane * 8;        // tau = w
    const unsigned short* bxB = wpkin + (w + 8) * 1024 + lane * 8;  // tau = w+8

    // clamped wave-uniform prefetch indices (every thread issues both loads)
    const int ixc = (tid < CPB * NX) ? tid : (CPB * NX - 1);
    const int iyc = (tid < CPB)      ? tid : (CPB - 1);

    // raw barrier: orders LDS (lgkm) only; VMEM (reg dests) stays in flight.
#define BAR()                                                           \
    do {                                                                \
        asm volatile("s_waitcnt lgkmcnt(0)" ::: "memory");              \
        __builtin_amdgcn_sched_barrier(0);                              \
        __builtin_amdgcn_s_barrier();                                   \
        __builtin_amdgcn_sched_barrier(0);                              \
    } while (0)

    // zero-init LDS (h planes must be 0 at t=0; pad cols stay 0 forever)
    {
        unsigned int* p;
        p = (unsigned int*)&Agh[0][0];
        for (int i = tid; i < 16 * 256; i += THREADS) p[i] = 0u;
        p = (unsigned int*)&Agl[0][0];
        for (int i = tid; i < 16 * 256; i += THREADS) p[i] = 0u;
        if (tid < 256) ((unsigned int*)&Xh[0])[tid] = 0u;
        if (tid < 256) ((unsigned int*)&Xl[0])[tid] = 0u;
    }

    // ---- prologue: LDS-persisted weights for both groups
    //      (pi15 q0-3 -> BwB, pi14 q0-2 -> BwA), x/y for t=0
    {
        int wg = w * 2;
        *(v8s*)&BwB[wg][0 * 512 + lane * 8] = *(const v8s*)(gbaseA + 61440);
        *(v8s*)&BwB[wg][1 * 512 + lane * 8] = *(const v8s*)(gbaseA + 62464);
        *(v8s*)&BwB[wg][2 * 512 + lane * 8] = *(const v8s*)(gbaseA + 63488);
        *(v8s*)&BwB[wg][3 * 512 + lane * 8] = *(const v8s*)(gbaseA + 64512);
        *(v8s*)&BwA[wg][0 * 512 + lane * 8] = *(const v8s*)(gbaseA + 57344);
        *(v8s*)&BwA[wg][1 * 512 + lane * 8] = *(const v8s*)(gbaseA + 58368);
        *(v8s*)&BwA[wg][2 * 512 + lane * 8] = *(const v8s*)(gbaseA + 59392);
        wg = w * 2 + 1;
        *(v8s*)&BwB[wg][0 * 512 + lane * 8] = *(const v8s*)(gbaseB + 61440);
        *(v8s*)&BwB[wg][1 * 512 + lane * 8] = *(const v8s*)(gbaseB + 62464);
        *(v8s*)&BwB[wg][2 * 512 + lane * 8] = *(const v8s*)(gbaseB + 63488);
        *(v8s*)&BwB[wg][3 * 512 + lane * 8] = *(const v8s*)(gbaseB + 64512);
        *(v8s*)&BwA[wg][0 * 512 + lane * 8] = *(const v8s*)(gbaseB + 57344);
        *(v8s*)&BwA[wg][1 * 512 + lane * 8] = *(const v8s*)(gbaseB + 58368);
        *(v8s*)&BwA[wg][2 * 512 + lane * 8] = *(const v8s*)(gbaseB + 59392);
    }

    float xv = x[(size_t)g0 * NX + ixc];
    float yv = y[(size_t)g0 + iyc];

    float c_stA[4], c_stB[4];
    #pragma unroll
    for (int r = 0; r < 4; ++r) { c_stA[r] = 0.0f; c_stB[r] = 0.0f; }

    // 2-pi-deep rotating stream buffers (named, static uses only)
    v8s aA0, aA1, aA2, aA3, aB0, aB1, aB2, aB3;   // pi p   (even)
    v8s bA0, bA1, bA2, bA3, bB0, bB1, bB2, bB3;   // pi p+1 (odd)
    v8s q3A, q3B;
    const char* pa = gbaseA;                      // group-A stream ptr
    const char* pb = gbaseB;                      // group-B stream ptr

#define ISSA(P)                                                         \
    do {                                                                \
        P##0 = *(const v8s*)(pa);        P##1 = *(const v8s*)(pa + 1024); \
        P##2 = *(const v8s*)(pa + 2048); P##3 = *(const v8s*)(pa + 3072); \
        pa += 4096;                                                     \
    } while (0)
#define ISSB(P)                                                         \
    do {                                                                \
        P##0 = *(const v8s*)(pb);        P##1 = *(const v8s*)(pb + 1024); \
        P##2 = *(const v8s*)(pb + 2048); P##3 = *(const v8s*)(pb + 3072); \
        pb += 4096;                                                     \
    } while (0)

    // one pi for BOTH groups: A-fragment shared, 16 MFMAs
#define GEMM2(PI, PA, PB)                                               \
    do {                                                                \
        v8s Ah = *(const v8s*)&Agh[PI][lane * 8];                       \
        v8s Al = *(const v8s*)&Agl[PI][lane * 8];                       \
        accA0 = MFMA_BF16(Ah, PA##0, accA0, 0, 0, 0);                   \
        accA0 = MFMA_BF16(Al, PA##0, accA0, 0, 0, 0);                   \
        accA1 = MFMA_BF16(Ah, PA##1, accA1, 0, 0, 0);                   \
        accA1 = MFMA_BF16(Al, PA##1, accA1, 0, 0, 0);                   \
        accA2 = MFMA_BF16(Ah, PA##2, accA2, 0, 0, 0);                   \
        accA2 = MFMA_BF16(Al, PA##2, accA2, 0, 0, 0);                   \
        accA3 = MFMA_BF16(Ah, PA##3, accA3, 0, 0, 0);                   \
        accA3 = MFMA_BF16(Al, PA##3, accA3, 0, 0, 0);                   \
        accB0 = MFMA_BF16(Ah, PB##0, accB0, 0, 0, 0);                   \
        accB0 = MFMA_BF16(Al, PB##0, accB0, 0, 0, 0);                   \
        accB1 = MFMA_BF16(Ah, PB##1, accB1, 0, 0, 0);                   \
        accB1 = MFMA_BF16(Al, PB##1, accB1, 0, 0, 0);                   \
        accB2 = MFMA_BF16(Ah, PB##2, accB2, 0, 0, 0);                   \
        accB2 = MFMA_BF16(Al, PB##2, accB2, 0, 0, 0);                   \
        accB3 = MFMA_BF16(Ah, PB##3, accB3, 0, 0, 0);                   \
        accB3 = MFMA_BF16(Al, PB##3, accB3, 0, 0, 0);                   \
    } while (0)

    ISSA(aA); ISSB(aB);      // pi 0 for both groups (fly across prologue BAR)
    ISSA(bA); ISSB(bB);      // pi 1
    BAR();                   // zero-init + persisted LDS visible (lgkm only)

    #pragma unroll 1
    for (int t = 0; t < NT; ++t) {
        // ---- P1': stage xcat from prefetched regs (pure LDS writes)
        if (tid < CPB * NX) {
            float v  = xv;
            int cell = tid / NX;
            int k    = tid - cell * NX;
            int pos  = (((k >> 3) << 4) + cell) * 8 + (k & 7);
            unsigned short hi = f2bf(v);
            Xh[pos] = hi;
            Xl[pos] = f2bf(v - bf2f(hi));
        }
        if (tid < CPB) {
            if (!__builtin_isnan(yv)) {
                int pos = (2 * 16 + tid) * 8 + 4;     // k = 20
                unsigned short hi = f2bf(yv);
                Xh[pos] = hi;
                Xl[pos] = f2bf(yv - bf2f(hi));
            }
        }
        // w_in fragments for this step's X (fly across barrier A)
        v8s bxhA = *(const v8s*)bxA;
        v8s bxlA = *(const v8s*)(bxA + 512);
        v8s bxhB = *(const v8s*)bxB;
        v8s bxlB = *(const v8s*)(bxB + 512);
        BAR();                                         // barrier A (lgkm only)

        // ---- X: x0 = relu(xcat @ w_in^T + b_in); writes planes 8..15 only
        {
            v8s xah = *(const v8s*)&Xh[lane * 8];
            v8s xal = *(const v8s*)&Xl[lane * 8];
            v4f xaccA = {0.0f, 0.0f, 0.0f, 0.0f};
            v4f xaccB = {0.0f, 0.0f, 0.0f, 0.0f};
            xaccA = MFMA_BF16(xah, bxhA, xaccA, 0, 0, 0);
            xaccA = MFMA_BF16(xah, bxlA, xaccA, 0, 0, 0);
            xaccA = MFMA_BF16(xal, bxhA, xaccA, 0, 0, 0);
            xaccB = MFMA_BF16(xah, bxhB, xaccB, 0, 0, 0);
            xaccB = MFMA_BF16(xah, bxlB, xaccB, 0, 0, 0);
            xaccB = MFMA_BF16(xal, bxhB, xaccB, 0, 0, 0);
            #pragma unroll
            for (int r = 0; r < 4; ++r) {
                int cell = quad * 4 + r;
                if (cell < CPB) {
                    int pos = (qp_w * 16 + cell) * 8 + e_w;
                    float vA = fmaxf(xaccA[r] + bi_xA, 0.0f);
                    unsigned short hiA = f2bf(vA);
                    Agh[pi_xA][pos] = hiA;
                    Agl[pi_xA][pos] = f2bf(vA - bf2f(hiA));
                    float vB = fmaxf(xaccB[r] + bi_xB, 0.0f);
                    unsigned short hiB = f2bf(vB);
                    Agh[pi_xB][pos] = hiB;
                    Agl[pi_xB][pos] = f2bf(vB - bf2f(hiB));
                }
            }
        }
        // no barrier: G1 reads planes 0..7 -- disjoint from X's writes

        // ---- G1: h-planes pi 0..7, 2-pi-deep register pipeline
        v4f accA0 = {0,0,0,0}, accA1 = {0,0,0,0}, accA2 = {0,0,0,0}, accA3 = {0,0,0,0};
        v4f accB0 = {0,0,0,0}, accB1 = {0,0,0,0}, accB2 = {0,0,0,0}, accB3 = {0,0,0,0};

        GEMM2(0, aA, aB);  ISSA(aA); ISSB(aB);   // issue pi 2
        GEMM2(1, bA, bB);  ISSA(bA); ISSB(bB);   // issue pi 3
        GEMM2(2, aA, aB);  ISSA(aA); ISSB(aB);   // issue pi 4
        GEMM2(3, bA, bB);  ISSA(bA); ISSB(bB);   // issue pi 5
        GEMM2(4, aA, aB);  ISSA(aA); ISSB(aB);   // issue pi 6
        GEMM2(5, bA, bB);  ISSA(bA); ISSB(bB);   // issue pi 7
        GEMM2(6, aA, aB);  ISSA(aA); ISSB(aB);   // issue pi 8
        GEMM2(7, bA, bB);  ISSA(bA); ISSB(bB);   // issue pi 9
        BAR();                                         // barrier B (orders X)

        // ---- prefetch x/y for t+1 (wave-uniform; consumed next P1')
        {
            const int tn = (t + 1 < NT) ? (t + 1) : t;
            xv = x[((size_t)tn * NGRID + g0) * NX + ixc];
            yv = y[(size_t)tn * NGRID + g0 + iyc];
        }

        // ---- G2: x-planes pi 8..15 (x0 ordered by barrier B)
        GEMM2(8,  aA, aB); ISSA(aA); ISSB(aB);   // issue pi 10
        GEMM2(9,  bA, bB); ISSA(bA); ISSB(bB);   // issue pi 11
        GEMM2(10, aA, aB); ISSA(aA); ISSB(aB);   // issue pi 12
        GEMM2(11, bA, bB); ISSA(bA); ISSB(bB);   // issue pi 13
        GEMM2(12, aA, aB);
        q3A = *(const v8s*)(gbaseA + 60416);     // pi14-q3 chunks
        q3B = *(const v8s*)(gbaseB + 60416);
        GEMM2(13, bA, bB);
        pa = gbaseA; pb = gbaseB;                // wrap stream for next step
        ISSA(aA); ISSB(aB);                      // next step's pi 0
        ISSA(bA); ISSB(bB);                      // next step's pi 1

        // pi 14: q0-2 from BwA, q3 from streamed regs -- zero L2 traffic
        {
            v8s Ah = *(const v8s*)&Agh[14][lane * 8];
            v8s Al = *(const v8s*)&Agl[14][lane * 8];
            v8s c0 = *(const v8s*)&BwA[w * 2][0 * 512 + lane * 8];
            v8s c1 = *(const v8s*)&BwA[w * 2][1 * 512 + lane * 8];
            v8s c2 = *(const v8s*)&BwA[w * 2][2 * 512 + lane * 8];
            accA0 = MFMA_BF16(Ah, c0, accA0, 0, 0, 0);
            accA0 = MFMA_BF16(Al, c0, accA0, 0, 0, 0);
            accA1 = MFMA_BF16(Ah, c1, accA1, 0, 0, 0);
            accA1 = MFMA_BF16(Al, c1, accA1, 0, 0, 0);
            accA2 = MFMA_BF16(Ah, c2, accA2, 0, 0, 0);
            accA2 = MFMA_BF16(Al, c2, accA2, 0, 0, 0);
            accA3 = MFMA_BF16(Ah, q3A, accA3, 0, 0, 0);
            accA3 = MFMA_BF16(Al, q3A, accA3, 0, 0, 0);
            v8s d0 = *(const v8s*)&BwA[w * 2 + 1][0 * 512 + lane * 8];
            v8s d1 = *(const v8s*)&BwA[w * 2 + 1][1 * 512 + lane * 8];
            v8s d2 = *(const v8s*)&BwA[w * 2 + 1][2 * 512 + lane * 8];
            accB0 = MFMA_BF16(Ah, d0, accB0, 0, 0, 0);
            accB0 = MFMA_BF16(Al, d0, accB0, 0, 0, 0);
            accB1 = MFMA_BF16(Ah, d1, accB1, 0, 0, 0);
            accB1 = MFMA_BF16(Al, d1, accB1, 0, 0, 0);
            accB2 = MFMA_BF16(Ah, d2, accB2, 0, 0, 0);
            accB2 = MFMA_BF16(Al, d2, accB2, 0, 0, 0);
            accB3 = MFMA_BF16(Ah, q3B, accB3, 0, 0, 0);
            accB3 = MFMA_BF16(Al, q3B, accB3, 0, 0, 0);
        }
        // pi 15: all from BwB -- zero L2 traffic
        {
            v8s Ah = *(const v8s*)&Agh[15][lane * 8];
            v8s Al = *(const v8s*)&Agl[15][lane * 8];
            v8s c0 = *(const v8s*)&BwB[w * 2][0 * 512 + lane * 8];
            v8s c1 = *(const v8s*)&BwB[w * 2][1 * 512 + lane * 8];
            v8s c2 = *(const v8s*)&BwB[w * 2][2 * 512 + lane * 8];
            v8s c3 = *(const v8s*)&BwB[w * 2][3 * 512 + lane * 8];
            accA0 = MFMA_BF16(Ah, c0, accA0, 0, 0, 0);
            accA0 = MFMA_BF16(Al, c0, accA0, 0, 0, 0);
            accA1 = MFMA_BF16(Ah, c1, accA1, 0, 0, 0);
            accA1 = MFMA_BF16(Al, c1, accA1, 0, 0, 0);
            accA2 = MFMA_BF16(Ah, c2, accA2, 0, 0, 0);
            accA2 = MFMA_BF16(Al, c2, accA2, 0, 0, 0);
            accA3 = MFMA_BF16(Ah, c3, accA3, 0, 0, 0);
            accA3 = MFMA_BF16(Al, c3, accA3, 0, 0, 0);
            v8s d0 = *(const v8s*)&BwB[w * 2 + 1][0 * 512 + lane * 8];
            v8s d1 = *(const v8s*)&BwB[w * 2 + 1][1 * 512 + lane * 8];
            v8s d2 = *(const v8s*)&BwB[w * 2 + 1][2 * 512 + lane * 8];
            v8s d3 = *(const v8s*)&BwB[w * 2 + 1][3 * 512 + lane * 8];
            accB0 = MFMA_BF16(Ah, d0, accB0, 0, 0, 0);
            accB0 = MFMA_BF16(Al, d0, accB0, 0, 0, 0);
            accB1 = MFMA_BF16(Ah, d1, accB1, 0, 0, 0);
            accB1 = MFMA_BF16(Al, d1, accB1, 0, 0, 0);
            accB2 = MFMA_BF16(Ah, d2, accB2, 0, 0, 0);
            accB2 = MFMA_BF16(Al, d2, accB2, 0, 0, 0);
            accB3 = MFMA_BF16(Ah, d3, accB3, 0, 0, 0);
            accB3 = MFMA_BF16(Al, d3, accB3, 0, 0, 0);
        }

        // ---- E: pointwise LSTM for both groups + h writeback + y partials
        // (E writes planes 0..7; all reads of 0..7 finished before barrier B)
        {
            float ypA[4], ypB[4];
            #pragma unroll
            for (int r = 0; r < 4; ++r) {
                int cell = quad * 4 + r;
                int pos  = (qp_w * 16 + cell) * 8 + e_w;
                float iv = accA0[r] + b_iA;
                float fv = accA1[r] + b_fA;
                float gv = accA2[r] + b_gA;
                float ov = accA3[r] + b_oA;
                float c  = fmaf(sigm(fv), c_stA[r], sigm(iv) * tanh_f(gv));
                c_stA[r] = c;
                float hA = sigm(ov) * tanh_f(c);
                ypA[r] = 0.0f;
                if (cell < CPB) {
                    unsigned short hi = f2bf(hA);
                    Agh[pi_hA][pos] = hi;
                    Agl[pi_hA][pos] = f2bf(hA - bf2f(hi));
                    ypA[r] = hA * woA;
                }
                iv = accB0[r] + b_iB;
                fv = accB1[r] + b_fB;
                gv = accB2[r] + b_gB;
                ov = accB3[r] + b_oB;
                c  = fmaf(sigm(fv), c_stB[r], sigm(iv) * tanh_f(gv));
                c_stB[r] = c;
                float hB = sigm(ov) * tanh_f(c);
                ypB[r] = 0.0f;
                if (cell < CPB) {
                    unsigned short hi = f2bf(hB);
                    Agh[pi_hB][pos] = hi;
                    Agl[pi_hB][pos] = f2bf(hB - bf2f(hi));
                    ypB[r] = hB * woB;
                }
            }
            #pragma unroll
            for (int r = 0; r < 4; ++r) {
                float p = ypA[r];
                p += __shfl_xor(p, 1);
                p += __shfl_xor(p, 2);
                p += __shfl_xor(p, 4);
                p += __shfl_xor(p, 8);
                if (col == 0) y_part[w][quad * 4 + r] = p;
                float q = ypB[r];
                q += __shfl_xor(q, 1);
                q += __shfl_xor(q, 2);
                q += __shfl_xor(q, 4);
                q += __shfl_xor(q, 8);
                if (col == 0) y_part[w + 8][quad * 4 + r] = q;
            }
        }
        BAR();                                         // barrier C (lgkm only)

        // ---- P5: finalize y, store, feed back into xcat k=20
        // (next barrier A orders these LDS writes vs next X reads;
        //  k=20 obs overwrite next P1' is same-thread)
        if (tid < CPB) {
            float yfin = bout;
            #pragma unroll
            for (int w2 = 0; w2 < 16; ++w2) yfin += y_part[w2][tid];
            out[(size_t)t * NGRID + g0 + tid] = yfin;
            int pos = (2 * 16 + tid) * 8 + 4;             // k = 20
            unsigned short hi = f2bf(yfin);
            Xh[pos] = hi;
            Xl[pos] = f2bf(yfin - bf2f(hi));
        }
    }
}

extern "C" void kernel_launch(void* const* d_in, const int* in_sizes, int n_in,
                              void* d_out, int out_size, void* d_ws, size_t ws_size,
                              hipStream_t stream) {
    const float* x     = (const float*)d_in[0];
    const float* y     = (const float*)d_in[1];
    const float* w_in  = (const float*)d_in[2];
    const float* b_in  = (const float*)d_in[3];
    const float* w_ih  = (const float*)d_in[4];
    const float* b_ih  = (const float*)d_in[5];
    const float* w_hh  = (const float*)d_in[6];
    const float* b_hh  = (const float*)d_in[7];
    const float* w_out = (const float*)d_in[8];
    const float* b_out = (const float*)d_in[9];

    unsigned short* wpk   = (unsigned short*)d_ws;
    unsigned short* wpkin = wpk + WPK_US;
    float*          bsum  = (float*)(wpkin + WPKIN_US);
    float*          out   = (float*)d_out;

    prep_kernel<<<(WPK_US + 255) / 256, 256, 0, stream>>>(
        w_in, w_ih, w_hh, b_ih, b_hh, wpk, wpkin, bsum);
    lstm_main<<<NBLK, THREADS, 0, stream>>>(
        x, y, b_in, w_out, b_out, wpk, wpkin, bsum, out);
}

// Round 8
// 4000.015 us; speedup vs baseline: 3.2354x; 3.2354x over previous
//
#include <hip/hip_runtime.h>
#include <math.h>

#define NT     365
#define NGRID  3000
#define NX     20
#define H      256
#define CPB    15
#define NBLK   (NGRID/CPB)     // 200 blocks, 1 per CU
#define THREADS 1024           // 16 waves, 4 per SIMD

// packed weight sizes (ushorts)
// wpk HI-ONLY: [g 16][kap 16][q 4][lane 64][e 8]
#define WPK_US   (16*16*4*64*8)   // 524,288
#define WPKIN_US (16*2*64*8)      // 16,384

typedef short v8s __attribute__((ext_vector_type(8)));
typedef float v4f __attribute__((ext_vector_type(4)));
#define MFMA_BF16 __builtin_amdgcn_mfma_f32_16x16x32_bf16

__device__ __forceinline__ unsigned short f2bf(float f) {
    unsigned int u = __float_as_uint(f);
    u += 0x7fffu + ((u >> 16) & 1u);          // RTNE
    return (unsigned short)(u >> 16);
}
__device__ __forceinline__ float bf2f(unsigned short h) {
    return __uint_as_float(((unsigned int)h) << 16);
}
__device__ __forceinline__ float sigm(float x)  { return 1.0f / (1.0f + __expf(-x)); }
__device__ __forceinline__ float tanh_f(float x){ return 2.0f * sigm(2.0f * x) - 1.0f; }

// ---------------- weight pre-pack (identical to R2 champion) ----------------
__global__ void prep_kernel(const float* __restrict__ w_in,
                            const float* __restrict__ w_ih,
                            const float* __restrict__ w_hh,
                            const float* __restrict__ b_ih,
                            const float* __restrict__ b_hh,
                            unsigned short* __restrict__ wpk,
                            unsigned short* __restrict__ wpkin,
                            float* __restrict__ bsum) {
    int idx = blockIdx.x * 256 + threadIdx.x;
    if (idx < WPK_US) {
        int e    = idx & 7;
        int lane = (idx >> 3) & 63;
        int q    = (idx >> 9) & 3;
        int gk   = idx >> 11;            // 0..255
        int kap  = gk & 15, g = gk >> 4;
        int k = kap * 32 + ((lane >> 4) << 3) + e;
        int j = q * 256 + g * 16 + (lane & 15);
        float wv = (k < 256) ? w_ih[j * 256 + k] : w_hh[j * 256 + (k - 256)];
        wpk[idx] = f2bf(wv);             // hi only
    }
    if (idx < WPKIN_US) {
        int e    = idx & 7;
        int lane = (idx >> 3) & 63;
        int d    = (idx >> 9) & 1;
        int tau  = idx >> 10;            // 0..15
        int k = ((lane >> 4) << 3) + e;
        int n = tau * 16 + (lane & 15);
        float wv = (k < NX + 1) ? w_in[n * (NX + 1) + k] : 0.0f;
        unsigned short hi = f2bf(wv);
        wpkin[idx] = d ? f2bf(wv - bf2f(hi)) : hi;
    }
    if (idx < 4 * H) bsum[idx] = b_ih[idx] + b_hh[idx];
}

// ---------------- main persistent LSTM ----------------
// R16 = "R2-clean": the 3968us champion minus its two defects, zero new
// register pressure.  Session evidence (R1,R4,R5,R6,R7): every reg-resident
// weight scheme spills, and spills cost nonlinearly (scratch reads at L3
// latency on the critical path); gload_lds defeats L2 residency; raw
// lgkm-only barriers passed correctness 4x.
//  - NO register persistence: kaps 8,9 streamed like 12..15 (same bytes as
//    R2's scratch round-trip, but L2-hot and no WRITE traffic).
//  - LDS persists kap 11 full (64KB) + kap 10 q0-2 (48KB); kap-10 q3 is a
//    per-step streamed load issued before barrier A (long flight).
//  - raw lgkm barriers: q3/bx/x/y loads fly across them (no vmcnt(0) drain).
//  - bxh/bxl reloaded per step (L2-hot, hidden across barrier A).
// Stream 912 KB/step via L2 (~6.2us floor). Transient regs ~55 < 64.
__global__ __attribute__((amdgpu_flat_work_group_size(THREADS, THREADS),
                          amdgpu_waves_per_eu(4, 4)))
void lstm_main(const float* __restrict__ x,
               const float* __restrict__ y,
               const float* __restrict__ b_in,
               const float* __restrict__ w_out,
               const float* __restrict__ b_out,
               const unsigned short* __restrict__ wpk,
               const unsigned short* __restrict__ wpkin,
               const float* __restrict__ bsum,
               float* __restrict__ out) {
    // fragment-major activation buffers: [kap][lane*8+e], lane = qp*16 + m
    __shared__ __align__(16) unsigned short Agh[16][512];   // 16 KB
    __shared__ __align__(16) unsigned short Agl[16][512];   // 16 KB
    __shared__ __align__(16) unsigned short Xh[512];        // 1 KB
    __shared__ __align__(16) unsigned short Xl[512];        // 1 KB
    __shared__ __align__(16) unsigned short Bw11[16][2048]; // 64 KB kap-11
    __shared__ __align__(16) unsigned short Bw10[16][1536]; // 48 KB kap-10 q0-2
    __shared__ float y_part[16][16];
    // total ~147 KB -> 1 block/CU

    const int tid  = threadIdx.x;
    const int w    = tid >> 6;          // wave 0..15; owns output group g = w
    const int lane = tid & 63;
    const int col  = lane & 15;
    const int quad = lane >> 4;
    const int g0   = blockIdx.x * CPB;

    // per-wave constants: lane owns hidden index jh = w*16 + col
    const int   jh   = w * 16 + col;
    const float b_i  = bsum[jh];
    const float b_f  = bsum[256 + jh];
    const float b_g  = bsum[512 + jh];
    const float b_o  = bsum[768 + jh];
    const float wo   = w_out[jh];
    const float bi_x = b_in[jh];
    const float bout = b_out[0];
    const int   kq_x = jh >> 5;                   // x0 write plane (0..7)
    const int   kq_h = 8 + (jh >> 5);             // h write plane (8..15)
    const int   qp_w = (jh >> 3) & 3;
    const int   e_w  = jh & 7;
    const unsigned short* bbase = wpk + (size_t)(w * 16) * 4 * 512 + lane * 8;
    const unsigned short* q3p   = bbase + (size_t)(10 * 4 + 3) * 512;
    const unsigned short* bx_hi = wpkin + (w * 2 + 0) * 512 + lane * 8;
    const unsigned short* bx_lo = wpkin + (w * 2 + 1) * 512 + lane * 8;

    // raw barrier: orders LDS (lgkm) only; VMEM (reg dests) stays in flight.
    // All cross-wave deps at these barriers are ds_write -> barrier -> ds_read.
#define BAR()                                                           \
    do {                                                                \
        asm volatile("s_waitcnt lgkmcnt(0)" ::: "memory");              \
        __builtin_amdgcn_sched_barrier(0);                              \
        __builtin_amdgcn_s_barrier();                                   \
        __builtin_amdgcn_sched_barrier(0);                              \
    } while (0)

    // zero-init LDS (h planes must be 0 at t=0; pad cols stay 0 forever)
    {
        unsigned int* p;
        p = (unsigned int*)&Agh[0][0];
        for (int i = tid; i < 16 * 256; i += THREADS) p[i] = 0u;
        p = (unsigned int*)&Agl[0][0];
        for (int i = tid; i < 16 * 256; i += THREADS) p[i] = 0u;
        if (tid < 256) ((unsigned int*)&Xh[0])[tid] = 0u;
        if (tid < 256) ((unsigned int*)&Xl[0])[tid] = 0u;
    }

    // ---- prologue: LDS-persisted weights (kap 11 full, kap 10 q0-2),
    //      x/y for t=0 (one-time cost)
    {
        *(v8s*)&Bw11[w][0 * 512 + lane * 8] = *(const v8s*)(bbase + (11*4+0)*512);
        *(v8s*)&Bw11[w][1 * 512 + lane * 8] = *(const v8s*)(bbase + (11*4+1)*512);
        *(v8s*)&Bw11[w][2 * 512 + lane * 8] = *(const v8s*)(bbase + (11*4+2)*512);
        *(v8s*)&Bw11[w][3 * 512 + lane * 8] = *(const v8s*)(bbase + (11*4+3)*512);
        *(v8s*)&Bw10[w][0 * 512 + lane * 8] = *(const v8s*)(bbase + (10*4+0)*512);
        *(v8s*)&Bw10[w][1 * 512 + lane * 8] = *(const v8s*)(bbase + (10*4+1)*512);
        *(v8s*)&Bw10[w][2 * 512 + lane * 8] = *(const v8s*)(bbase + (10*4+2)*512);
    }

    float xv = 0.0f, yv = 0.0f;
    if (tid < CPB * NX) xv = x[(size_t)g0 * NX + tid];
    if (tid < CPB)      yv = y[(size_t)g0 + tid];

    float c_st[4];
    #pragma unroll
    for (int r = 0; r < 4; ++r) c_st[r] = 0.0f;
    BAR();      // zero-init + persisted LDS visible (lgkm only)

    // streamed kap: single-buffer, loads at top of body (R2 structure)
#define GEMM_S(KAP)                                                     \
    do {                                                                \
        const unsigned short* bp = bbase + (size_t)(KAP) * 4 * 512;     \
        v8s Bs0 = *(const v8s*)(bp + 0 * 512);                          \
        v8s Bs1 = *(const v8s*)(bp + 1 * 512);                          \
        v8s Bs2 = *(const v8s*)(bp + 2 * 512);                          \
        v8s Bs3 = *(const v8s*)(bp + 3 * 512);                          \
        v8s Ah  = *(const v8s*)&Agh[KAP][lane * 8];                     \
        v8s Al  = *(const v8s*)&Agl[KAP][lane * 8];                     \
        acc0 = MFMA_BF16(Ah, Bs0, acc0, 0, 0, 0);                       \
        acc0 = MFMA_BF16(Al, Bs0, acc0, 0, 0, 0);                       \
        acc1 = MFMA_BF16(Ah, Bs1, acc1, 0, 0, 0);                       \
        acc1 = MFMA_BF16(Al, Bs1, acc1, 0, 0, 0);                       \
        acc2 = MFMA_BF16(Ah, Bs2, acc2, 0, 0, 0);                       \
        acc2 = MFMA_BF16(Al, Bs2, acc2, 0, 0, 0);                       \
        acc3 = MFMA_BF16(Ah, Bs3, acc3, 0, 0, 0);                       \
        acc3 = MFMA_BF16(Al, Bs3, acc3, 0, 0, 0);                       \
    } while (0)

    #pragma unroll 1
    for (int t = 0; t < NT; ++t) {
        // ---- P1': stage xcat from prefetched regs (pure LDS writes)
        if (tid < CPB * NX) {
            float v  = xv;
            int cell = tid / NX;
            int k    = tid - cell * NX;
            int pos  = (((k >> 3) << 4) + cell) * 8 + (k & 7);
            unsigned short hi = f2bf(v);
            Xh[pos] = hi;
            Xl[pos] = f2bf(v - bf2f(hi));
        }
        if (tid < CPB) {
            if (!__builtin_isnan(yv)) {
                int pos = (2 * 16 + tid) * 8 + 4;     // k = 20
                unsigned short hi = f2bf(yv);
                Xh[pos] = hi;
                Xl[pos] = f2bf(yv - bf2f(hi));
            }
        }
        // per-step loads that fly across barrier A (+ X phase):
        v8s q3v = *(const v8s*)q3p;             // kap-10 q3
        v8s bxh = *(const v8s*)bx_hi;           // w_in fragments
        v8s bxl = *(const v8s*)bx_lo;
        BAR();                                         // barrier A (lgkm only)

        // ---- X: x0 = relu(xcat @ w_in^T + b_in); writes planes 0..7 only
        {
            v8s xah = *(const v8s*)&Xh[lane * 8];
            v8s xal = *(const v8s*)&Xl[lane * 8];
            v4f xacc = {0.0f, 0.0f, 0.0f, 0.0f};
            xacc = MFMA_BF16(xah, bxh, xacc, 0, 0, 0);
            xacc = MFMA_BF16(xah, bxl, xacc, 0, 0, 0);
            xacc = MFMA_BF16(xal, bxh, xacc, 0, 0, 0);
            #pragma unroll
            for (int r = 0; r < 4; ++r) {
                int cell = quad * 4 + r;
                if (cell < CPB) {
                    float v = fmaxf(xacc[r] + bi_x, 0.0f);
                    unsigned short hi = f2bf(v);
                    int pos = (qp_w * 16 + cell) * 8 + e_w;
                    Agh[kq_x][pos] = hi;
                    Agl[kq_x][pos] = f2bf(v - bf2f(hi));
                }
            }
        }
        // no barrier: G1 reads planes 8..15, disjoint from X's writes

        // ---- G1: h-kaps -- LDS kaps 10,11 first (streamed loads land
        //      meanwhile), then streamed kaps 8,9,12..15
        v4f acc0 = {0.0f, 0.0f, 0.0f, 0.0f};
        v4f acc1 = {0.0f, 0.0f, 0.0f, 0.0f};
        v4f acc2 = {0.0f, 0.0f, 0.0f, 0.0f};
        v4f acc3 = {0.0f, 0.0f, 0.0f, 0.0f};

        // kap 10: q0-2 from LDS, q3 from streamed q3v -- zero L2 traffic
        {
            v8s Bl0 = *(const v8s*)&Bw10[w][0 * 512 + lane * 8];
            v8s Bl1 = *(const v8s*)&Bw10[w][1 * 512 + lane * 8];
            v8s Bl2 = *(const v8s*)&Bw10[w][2 * 512 + lane * 8];
            v8s Ah  = *(const v8s*)&Agh[10][lane * 8];
            v8s Al  = *(const v8s*)&Agl[10][lane * 8];
            acc0 = MFMA_BF16(Ah, Bl0, acc0, 0, 0, 0);
            acc0 = MFMA_BF16(Al, Bl0, acc0, 0, 0, 0);
            acc1 = MFMA_BF16(Ah, Bl1, acc1, 0, 0, 0);
            acc1 = MFMA_BF16(Al, Bl1, acc1, 0, 0, 0);
            acc2 = MFMA_BF16(Ah, Bl2, acc2, 0, 0, 0);
            acc2 = MFMA_BF16(Al, Bl2, acc2, 0, 0, 0);
            acc3 = MFMA_BF16(Ah, q3v, acc3, 0, 0, 0);
            acc3 = MFMA_BF16(Al, q3v, acc3, 0, 0, 0);
        }
        // kap 11 from LDS -- zero L2 traffic
        {
            v8s Bl0 = *(const v8s*)&Bw11[w][0 * 512 + lane * 8];
            v8s Bl1 = *(const v8s*)&Bw11[w][1 * 512 + lane * 8];
            v8s Bl2 = *(const v8s*)&Bw11[w][2 * 512 + lane * 8];
            v8s Bl3 = *(const v8s*)&Bw11[w][3 * 512 + lane * 8];
            v8s Ah  = *(const v8s*)&Agh[11][lane * 8];
            v8s Al  = *(const v8s*)&Agl[11][lane * 8];
            acc0 = MFMA_BF16(Ah, Bl0, acc0, 0, 0, 0);
            acc0 = MFMA_BF16(Al, Bl0, acc0, 0, 0, 0);
            acc1 = MFMA_BF16(Ah, Bl1, acc1, 0, 0, 0);
            acc1 = MFMA_BF16(Al, Bl1, acc1, 0, 0, 0);
            acc2 = MFMA_BF16(Ah, Bl2, acc2, 0, 0, 0);
            acc2 = MFMA_BF16(Al, Bl2, acc2, 0, 0, 0);
            acc3 = MFMA_BF16(Ah, Bl3, acc3, 0, 0, 0);
            acc3 = MFMA_BF16(Al, Bl3, acc3, 0, 0, 0);
        }
        // streamed h-kaps
        GEMM_S(8);
        GEMM_S(9);
        #pragma unroll 1
        for (int kap = 12; kap < 16; ++kap) GEMM_S(kap);
        BAR();                                         // barrier B (orders X)

        // ---- prefetch x/y for t+1 (flies across barrier C into next P1')
        {
            const int tn = (t + 1 < NT) ? (t + 1) : t;
            if (tid < CPB * NX)
                xv = x[((size_t)tn * NGRID + g0) * NX + tid];
            if (tid < CPB)
                yv = y[(size_t)tn * NGRID + g0 + tid];
        }

        // ---- G2: x-kaps 0..7 (x0 ordered by barrier B)
        #pragma unroll 1
        for (int kap = 0; kap < 8; ++kap) GEMM_S(kap);

        // ---- E: pointwise LSTM + h writeback + y partial
        // (E writes planes 8..15; all reads of 8..15 ended before barrier B)
        {
            float yp[4];
            #pragma unroll
            for (int r = 0; r < 4; ++r) {
                int cell = quad * 4 + r;
                float iv = acc0[r] + b_i;
                float fv = acc1[r] + b_f;
                float gv = acc2[r] + b_g;
                float ov = acc3[r] + b_o;
                float c  = fmaf(sigm(fv), c_st[r], sigm(iv) * tanh_f(gv));
                c_st[r]  = c;
                float h  = sigm(ov) * tanh_f(c);
                yp[r] = 0.0f;
                if (cell < CPB) {
                    unsigned short hi = f2bf(h);
                    int pos = (qp_w * 16 + cell) * 8 + e_w;
                    Agh[kq_h][pos] = hi;
                    Agl[kq_h][pos] = f2bf(h - bf2f(hi));
                    yp[r] = h * wo;
                }
            }
            #pragma unroll
            for (int r = 0; r < 4; ++r) {
                float p = yp[r];
                p += __shfl_xor(p, 1);
                p += __shfl_xor(p, 2);
                p += __shfl_xor(p, 4);
                p += __shfl_xor(p, 8);
                if (col == 0)
                    y_part[w][quad * 4 + r] = p;
            }
        }
        BAR();                                         // barrier C (lgkm only)

        // ---- P5: finalize y, store, feed back into xcat k=20
        // (next barrier A orders these LDS writes vs next X reads;
        //  k=20 obs overwrite next P1' is same-thread)
        if (tid < CPB) {
            float yfin = bout;
            #pragma unroll
            for (int w2 = 0; w2 < 16; ++w2) yfin += y_part[w2][tid];
            out[(size_t)t * NGRID + g0 + tid] = yfin;
            int pos = (2 * 16 + tid) * 8 + 4;             // k = 20
            unsigned short hi = f2bf(yfin);
            Xh[pos] = hi;
            Xl[pos] = f2bf(yfin - bf2f(hi));
        }
    }
}

extern "C" void kernel_launch(void* const* d_in, const int* in_sizes, int n_in,
                              void* d_out, int out_size, void* d_ws, size_t ws_size,
                              hipStream_t stream) {
    const float* x     = (const float*)d_in[0];
    const float* y     = (const float*)d_in[1];
    const float* w_in  = (const float*)d_in[2];
    const float* b_in  = (const float*)d_in[3];
    const float* w_ih  = (const float*)d_in[4];
    const float* b_ih  = (const float*)d_in[5];
    const float* w_hh  = (const float*)d_in[6];
    const float* b_hh  = (const float*)d_in[7];
    const float* w_out = (const float*)d_in[8];
    const float* b_out = (const float*)d_in[9];

    unsigned short* wpk   = (unsigned short*)d_ws;
    unsigned short* wpkin = wpk + WPK_US;
    float*          bsum  = (float*)(wpkin + WPKIN_US);
    float*          out   = (float*)d_out;

    prep_kernel<<<(WPK_US + 255) / 256, 256, 0, stream>>>(
        w_in, w_ih, w_hh, b_ih, b_hh, wpk, wpkin, bsum);
    lstm_main<<<NBLK, THREADS, 0, stream>>>(
        x, y, b_in, w_out, b_out, wpk, wpkin, bsum, out);
}